// Round 1
// baseline (108.877 us; speedup 1.0000x reference)
//
#include <hip/hip_runtime.h>
#include <hip/hip_bf16.h>

#define N 8192
#define D 128
#define NJB 64  // column blocks of 128

typedef __bf16 bf16x8 __attribute__((ext_vector_type(8)));
typedef float f32x4 __attribute__((ext_vector_type(4)));

// Kernel 1: row-normalize features (fp32 -> bf16), build label histogram.
__global__ void k_norm(const float* __restrict__ feat, const int* __restrict__ lab,
                       __hip_bfloat16* __restrict__ fbf, float* __restrict__ hist) {
    const int row  = blockIdx.x * 4 + (threadIdx.x >> 6);
    const int lane = threadIdx.x & 63;
    float2 v = *reinterpret_cast<const float2*>(&feat[row * D + lane * 2]);
    float ss = v.x * v.x + v.y * v.y;
#pragma unroll
    for (int m = 32; m; m >>= 1) ss += __shfl_xor(ss, m);
    const float r = 1.0f / fmaxf(sqrtf(ss), 1e-8f);
    __hip_bfloat162 o;
    o.x = __float2bfloat16(v.x * r);
    o.y = __float2bfloat16(v.y * r);
    *reinterpret_cast<__hip_bfloat162*>(&fbf[row * D + lane * 2]) = o;
    if (lane == 0) atomicAdd(&hist[lab[row]], 1.0f);  // exact fp32 counts
}

// Kernel 2: fused 128x128 MFMA tile + contrastive epilogue.
// Per block (ib,jb): sim tile = f[i0:i0+128] . f[j0:j0+128]^T via 16x16x32 bf16 MFMA,
// epilogue accumulates per-row: spos = sum logits over same-label cols,
// edem = sum exp(logits) over diff-label cols. Deterministic partial writes.
__launch_bounds__(256, 2)
__global__ void k_gemm(const __hip_bfloat16* __restrict__ fbf,
                       const int* __restrict__ lab,
                       const float* __restrict__ tempp,
                       float* __restrict__ Pspos, float* __restrict__ Pedem) {
    extern __shared__ char smem[];
    char* As = smem;           // 128 rows x 128 k bf16, XOR-swizzled (32 KB)
    char* Bs = smem + 32768;   // same for column block (32 KB)
    const int jb = blockIdx.x, ib = blockIdx.y;
    const int i0 = ib * 128, j0 = jb * 128;
    const int tid = threadIdx.x;

    const __hip_bfloat16* ga = fbf + i0 * D;
    const __hip_bfloat16* gb = fbf + j0 * D;
#pragma unroll
    for (int it = 0; it < 8; ++it) {
        int c = it * 256 + tid;         // 16B-chunk index: 128 rows x 16 chunks
        int row = c >> 4, kc = c & 15;
        int wb = row * 256 + ((kc ^ (row & 7)) << 4);  // st-style XOR swizzle (G4)
        *reinterpret_cast<uint4*>(&As[wb]) =
            *reinterpret_cast<const uint4*>(&ga[row * D + kc * 8]);
        *reinterpret_cast<uint4*>(&Bs[wb]) =
            *reinterpret_cast<const uint4*>(&gb[row * D + kc * 8]);
    }
    __syncthreads();

    const int wave = tid >> 6, lane = tid & 63;
    const int wm = wave >> 1, wn = wave & 1;   // 2x2 waves, 64x64 each
    const int lr = lane & 15, lg = lane >> 4;

    f32x4 acc[4][4] = {};
#pragma unroll
    for (int ks = 0; ks < 4; ++ks) {
        bf16x8 af[4], bfr[4];
#pragma unroll
        for (int mi = 0; mi < 4; ++mi) {
            int row = wm * 64 + mi * 16 + lr;
            int kc = ks * 4 + lg;
            af[mi] = *reinterpret_cast<const bf16x8*>(
                &As[row * 256 + ((kc ^ (row & 7)) << 4)]);
        }
#pragma unroll
        for (int ni = 0; ni < 4; ++ni) {
            int row = wn * 64 + ni * 16 + lr;
            int kc = ks * 4 + lg;
            bfr[ni] = *reinterpret_cast<const bf16x8*>(
                &Bs[row * 256 + ((kc ^ (row & 7)) << 4)]);
        }
#pragma unroll
        for (int mi = 0; mi < 4; ++mi)
#pragma unroll
            for (int ni = 0; ni < 4; ++ni)
                acc[mi][ni] = __builtin_amdgcn_mfma_f32_16x16x32_bf16(
                    af[mi], bfr[ni], acc[mi][ni], 0, 0, 0);
    }
    __syncthreads();  // all LDS reads done; safe to alias epilogue arrays onto As

    const float invT = 1.0f / tempp[0];
    int labj[4];
#pragma unroll
    for (int ni = 0; ni < 4; ++ni) labj[ni] = lab[j0 + wn * 64 + ni * 16 + lr];

    float* sposL = reinterpret_cast<float*>(smem);         // [2][128]
    float* edemL = reinterpret_cast<float*>(smem + 1024);  // [2][128]

    // C/D layout (m89): col = lane&15, row = (lane>>4)*4 + reg
#pragma unroll
    for (int mi = 0; mi < 4; ++mi) {
#pragma unroll
        for (int r = 0; r < 4; ++r) {
            const int rowl = wm * 64 + mi * 16 + lg * 4 + r;
            const int li = lab[i0 + rowl];
            float ps = 0.0f, es = 0.0f;
#pragma unroll
            for (int ni = 0; ni < 4; ++ni) {
                float v = acc[mi][ni][r] * invT;
                bool same = (li == labj[ni]);
                ps += same ? v : 0.0f;
                es += same ? 0.0f : __expf(v);
            }
#pragma unroll
            for (int m = 1; m < 16; m <<= 1) {  // reduce across the 16 col lanes
                ps += __shfl_xor(ps, m);
                es += __shfl_xor(es, m);
            }
            if (lr == 0) {
                sposL[wn * 128 + rowl] = ps;
                edemL[wn * 128 + rowl] = es;
            }
        }
    }
    __syncthreads();
    if (tid < 128) {
        float ps = sposL[tid] + sposL[128 + tid];
        float es = edemL[tid] + edemL[128 + tid];
        Pspos[jb * N + i0 + tid] = ps;
        Pedem[jb * N + i0 + tid] = es;
    }
}

// Kernel 3: per-row combine over 64 column-blocks, then per-block partial sum.
__global__ void k_row(const float* __restrict__ Pspos, const float* __restrict__ Pedem,
                      const int* __restrict__ lab, const float* __restrict__ hist,
                      float* __restrict__ bsums) {
    const int i = blockIdx.x * 128 + threadIdx.x;
    float sp = 0.0f, ed = 0.0f;
    for (int jb = 0; jb < NJB; ++jb) {
        sp += Pspos[jb * N + i];
        ed += Pedem[jb * N + i];
    }
    const float cnt = hist[lab[i]];
    float term = sp / cnt - logf(ed);
#pragma unroll
    for (int m = 32; m; m >>= 1) term += __shfl_xor(term, m);
    __shared__ float s2[2];
    if ((threadIdx.x & 63) == 0) s2[threadIdx.x >> 6] = term;
    __syncthreads();
    if (threadIdx.x == 0) bsums[blockIdx.x] = s2[0] + s2[1];
}

// Kernel 4: final scalar.
__global__ void k_final(const float* __restrict__ bsums, float* __restrict__ out) {
    float v = bsums[threadIdx.x];  // 64 threads, 64 block sums
#pragma unroll
    for (int m = 32; m; m >>= 1) v += __shfl_xor(v, m);
    if (threadIdx.x == 0) out[0] = -(v / (float)N);
}

extern "C" void kernel_launch(void* const* d_in, const int* in_sizes, int n_in,
                              void* d_out, int out_size, void* d_ws, size_t ws_size,
                              hipStream_t stream) {
    const float* feat = (const float*)d_in[0];
    const int* lab    = (const int*)d_in[1];
    const float* temp = (const float*)d_in[2];
    float* out = (float*)d_out;
    char* ws = (char*)d_ws;

    __hip_bfloat16* fbf = (__hip_bfloat16*)ws;      // 2 MB normalized bf16
    float* hist  = (float*)(ws + 2097152);          // 512 B label histogram
    float* Pspos = (float*)(ws + 2097664);          // 2 MB partials [64][8192]
    float* Pedem = (float*)(ws + 4194816);          // 2 MB partials [64][8192]
    float* bsums = (float*)(ws + 6291968);          // 256 B

    hipMemsetAsync(hist, 0, 128 * sizeof(float), stream);
    k_norm<<<N / 4, 256, 0, stream>>>(feat, lab, fbf, hist);
    dim3 grid(NJB, N / 128);
    k_gemm<<<grid, 256, 65536, stream>>>(fbf, lab, temp, Pspos, Pedem);
    k_row<<<64, 128, 0, stream>>>(Pspos, Pedem, lab, hist, bsums);
    k_final<<<1, 64, 0, stream>>>(bsums, out);
}